// Round 6
// baseline (353.704 us; speedup 1.0000x reference)
//
#include <hip/hip_runtime.h>
#include <math.h>

// Problem constants (fixed by the reference)
#define NN 50000
#define EDG 800000
#define OUTC 76
#define NKB 68          // 272/4 k-blocks in the packed-W projection
#define NB  196         // scan blocks = ceil(NN/256)

// ws float offsets
#define CCW_OFF  0                     // NN*16  packed (xyz,cw) per channel
#define LFP_OFF  (CCW_OFF + NN*16)     // NN*16  [lf*9, 0,0,0, pooled*3, 0]
#define WK_OFF   (LFP_OFF + NN*16)     // NKB*256 k-major packed W
#define CNT_OFF  (WK_OFF + NKB*256)    // NN ints
#define CUR_OFF  (CNT_OFF + NN)        // 1 int cursor (+3 pad)
#define OFFS_OFF (CUR_OFF + 4)         // NN ints
#define PERM_OFF (OFFS_OFF + NN)       // EDG ints
#define ECOL_OFF (PERM_OFF + EDG)      // EDG ints

// ---------------- fused prep (nodes + WK) + histogram ----------------
__global__ void prep_hist_kernel(const float* __restrict__ coord,
                                 const float* __restrict__ cw,
                                 const float* __restrict__ W,
                                 const int* __restrict__ row,
                                 float* __restrict__ ccwp,
                                 float* __restrict__ lfp,
                                 float* __restrict__ wk,
                                 int* __restrict__ counts,
                                 int* __restrict__ perm, int E) {
    int t = blockIdx.x * blockDim.x + threadIdx.x;

    if (t < E) perm[t] = atomicAdd(&counts[row[t]], 1);

    if (t < NKB * 64) {
        int kb = t >> 6, d = t & 63;
        float tmp[4];
        #pragma unroll
        for (int km = 0; km < 4; ++km) {
            int k = kb * 4 + km;
            int kcol = (k < 256) ? k : ((k < 265) ? k + 8 : -1);
            tmp[km] = (kcol >= 0) ? W[d * 273 + kcol] : 0.f;
        }
        ((float4*)wk)[t] = make_float4(tmp[0], tmp[1], tmp[2], tmp[3]);
    }

    if (t >= NN) return;
    const float* cp = coord + (size_t)t * 12;
    float c0x = cp[0], c0y = cp[1], c0z = cp[2];
    float c1x = cp[3], c1y = cp[4], c1z = cp[5];
    float c2x = cp[6], c2y = cp[7], c2z = cp[8];
    float c3x = cp[9], c3y = cp[10], c3z = cp[11];
    const float* wv = cw + (size_t)t * 4;
    float w0 = wv[0], w1 = wv[1], w2 = wv[2], w3 = wv[3];

    float* cc = ccwp + (size_t)t * 16;
    cc[0] = c0x; cc[1] = c0y; cc[2] = c0z; cc[3] = w0;
    cc[4] = c1x; cc[5] = c1y; cc[6] = c1z; cc[7] = w1;
    cc[8] = c2x; cc[9] = c2y; cc[10] = c2z; cc[11] = w2;
    cc[12] = c3x; cc[13] = c3y; cc[14] = c3z; cc[15] = w3;

    float xx = c1x - c0x, xy = c1y - c0y, xz = c1z - c0z;
    float invx = 1.0f / (sqrtf(xx * xx + xy * xy + xz * xz) + 1e-8f);
    xx *= invx; xy *= invx; xz *= invx;
    float tx = c2x - c0x, ty = c2y - c0y, tz = c2z - c0z;
    float dp = tx * xx + ty * xy + tz * xz;
    float yx = tx - dp * xx, yy = ty - dp * xy, yz = tz - dp * xz;
    float invy = 1.0f / (sqrtf(yx * yx + yy * yy + yz * yz) + 1e-8f);
    yx *= invy; yy *= invy; yz *= invy;
    float zx = xy * yz - xz * yy;
    float zy = xz * yx - xx * yz;
    float zz = xx * yy - xy * yx;

    float m0 = (w0 != 0.f) ? 1.f : 0.f;
    float m1 = (w1 != 0.f) ? 1.f : 0.f;
    float m2 = (w2 != 0.f) ? 1.f : 0.f;
    float m3 = (w3 != 0.f) ? 1.f : 0.f;
    float cs = m0 + m1 + m2 + m3;      // ref divides directly (no clamp)
    float px = (c0x * m0 + c1x * m1 + c2x * m2 + c3x * m3) / cs;
    float py = (c0y * m0 + c1y * m1 + c2y * m2 + c3y * m3) / cs;
    float pz = (c0z * m0 + c1z * m1 + c2z * m2 + c3z * m3) / cs;

    float* lp = lfp + (size_t)t * 16;
    lp[0] = xx; lp[1] = yx; lp[2] = zx;
    lp[3] = xy; lp[4] = yy; lp[5] = zy;
    lp[6] = xz; lp[7] = yz; lp[8] = zz;
    lp[9] = 0.f; lp[10] = 0.f; lp[11] = 0.f;
    lp[12] = px; lp[13] = py; lp[14] = pz; lp[15] = 0.f;
}

// ---------------- segment allocation: block scan + one atomic ----------------
__global__ void scanalloc_kernel(const int* __restrict__ counts,
                                 int* __restrict__ cursor,
                                 int* __restrict__ offs) {
    int t = blockIdx.x * 256 + threadIdx.x;
    int v = (t < NN) ? counts[t] : 0;
    int lane = threadIdx.x & 63, wid = threadIdx.x >> 6;
    int x = v;
    #pragma unroll
    for (int d = 1; d < 64; d <<= 1) {
        int u = __shfl_up(x, d);
        x += (lane >= d) ? u : 0;
    }
    __shared__ int wtot[4];
    __shared__ int sbase;
    if (lane == 63) wtot[wid] = x;
    __syncthreads();
    if (threadIdx.x == 0)
        sbase = atomicAdd(cursor, wtot[0] + wtot[1] + wtot[2] + wtot[3]);
    __syncthreads();
    int wbase = 0;
    for (int i = 0; i < wid; ++i) wbase += wtot[i];
    if (t < NN) offs[t] = sbase + wbase + x - v;
}

__global__ void scatter_kernel(const int* __restrict__ row, const int* __restrict__ col,
                               const int* __restrict__ offs, const int* __restrict__ perm,
                               int* __restrict__ ecol, int E) {
    int e = blockIdx.x * blockDim.x + threadIdx.x;
    if (e >= E) return;
    ecol[offs[row[e]] + perm[e]] = col[e];
}

// ---------------- DPP wave-64 sum ----------------
__device__ __forceinline__ float wave_sum64(float x) {
    float v = x, t;
    t = __int_as_float(__builtin_amdgcn_update_dpp(0, __float_as_int(v), 0x111, 0xf, 0xf, true)); v += t;
    t = __int_as_float(__builtin_amdgcn_update_dpp(0, __float_as_int(v), 0x112, 0xf, 0xf, true)); v += t;
    t = __int_as_float(__builtin_amdgcn_update_dpp(0, __float_as_int(v), 0x114, 0xf, 0xf, true)); v += t;
    t = __int_as_float(__builtin_amdgcn_update_dpp(0, __float_as_int(v), 0x118, 0xf, 0xf, true)); v += t;
    t = __int_as_float(__builtin_amdgcn_update_dpp(0, __float_as_int(v), 0x142, 0xa, 0xf, true)); v += t;
    t = __int_as_float(__builtin_amdgcn_update_dpp(0, __float_as_int(v), 0x143, 0xc, 0xf, true)); v += t;
    return __int_as_float(__builtin_amdgcn_readlane(__float_as_int(v), 63));
}

#define SWZ(x, pat) __int_as_float(__builtin_amdgcn_ds_swizzle(__float_as_int(x), pat))
#define QPERM(x, pat) __int_as_float(__builtin_amdgcn_update_dpp(0, __float_as_int(x), pat, 0xf, 0xf, true))

// ---------------- main: one wave per node ----------------
__global__ __launch_bounds__(256, 6) void edge_kernel(
    const float* __restrict__ coord, const float* __restrict__ attr,
    const float* __restrict__ bvec,
    const float* __restrict__ ccw, const float* __restrict__ lfp,
    const float* __restrict__ wk,
    const int* __restrict__ offs, const int* __restrict__ counts,
    const int* __restrict__ ecol,
    float* __restrict__ out) {
    __shared__ float S[4][280];

    const int w = threadIdx.x >> 6;
    const int l = threadIdx.x & 63;
    const int l15 = l & 15;
    const int n = blockIdx.x * 4 + w;

    const int st = offs[n];
    const int deg = counts[n];
    const int en = st + deg;
    const int b0 = (l & 3) * 4;
    const int i4 = (l >> 2) & 3;
    const int j4 = l & 3;
    const int a  = l >> 2;

    // Ar[i][a] for this lane's a
    const float ArA0 = attr[(size_t)n * 64 + 0 * 16 + a];
    const float ArA1 = attr[(size_t)n * 64 + 1 * 16 + a];
    const float ArA2 = attr[(size_t)n * 64 + 2 * 16 + a];
    const float ArA3 = attr[(size_t)n * 64 + 3 * 16 + a];
    const float4 cown = ((const float4*)ccw)[n * 4 + i4];
    const float crx = cown.x, cry = cown.y, crz = cown.z, cwr = cown.w;
    const float lrv = lfp[(size_t)n * 16 + l15];
    const float lfmask = (l < 9) ? 1.f : 0.f;
    const float pmask  = (l >= 12 && l < 15) ? 1.f : 0.f;

    float ax = 0.f, ay = 0.f, az = 0.f, aw = 0.f;
    float sgeo = 0.f, invs = 0.f, sp = 0.f;

    const float4* CCW4 = (const float4*)ccw;

    for (int base = st; base < en; base += 64) {
        int bcnt = en - base; bcnt = bcnt > 64 ? 64 : bcnt;
        int idx = base + (l < bcnt ? l : bcnt - 1);
        int cvec = ecol[idx];

        int c = __builtin_amdgcn_readlane(cvec, 0);
        const float* ar0 = attr + (size_t)c * 64;
        float4 A0 = *(const float4*)(ar0 + b0);
        float4 A1 = *(const float4*)(ar0 + 16 + b0);
        float4 A2 = *(const float4*)(ar0 + 32 + b0);
        float4 A3 = *(const float4*)(ar0 + 48 + b0);
        float4 cc  = CCW4[c * 4 + j4];
        float  lcv = lfp[c * 16 + l15];

        for (int k = 0; k < bcnt; ++k) {
            // prefetch next edge (SGPR base + const voffset => minimal VALU)
            int kn = (k + 1 < bcnt) ? k + 1 : k;
            int c2 = __builtin_amdgcn_readlane(cvec, kn);
            const float* arn = attr + (size_t)c2 * 64;
            float4 An0 = *(const float4*)(arn + b0);
            float4 An1 = *(const float4*)(arn + 16 + b0);
            float4 An2 = *(const float4*)(arn + 32 + b0);
            float4 An3 = *(const float4*)(arn + 48 + b0);
            float4 ccn  = CCW4[c2 * 4 + j4];
            float  lcvn = lfp[c2 * 16 + l15];

            // distance entry M[i4][j4] (full 4x4 replica in each 16-lane row)
            float dx = crx - cc.x, dy = cry - cc.y, dz = crz - cc.z;
            float m = __builtin_amdgcn_sqrtf(fmaf(dx, dx, fmaf(dy, dy, dz * dz))) * cwr * cc.w;

            // M[i][j4] from row-lane 4i+j4 : lane' = (lane & 0x13) | (i<<2)
            float M0 = SWZ(m, 0x013);
            float M1 = SWZ(m, 0x093);
            float M2 = SWZ(m, 0x113);
            float M3 = SWZ(m, 0x193);

            // this lane's U[j4][a]
            float Uo = fmaf(ArA3, M3, fmaf(ArA2, M2, fmaf(ArA1, M1, ArA0 * M0)));
            // quad holds U[0..3][a] at lanes 4a+j -> quad_perm broadcast
            float U0 = QPERM(Uo, 0x00);
            float U1 = QPERM(Uo, 0x55);
            float U2 = QPERM(Uo, 0xAA);
            float U3 = QPERM(Uo, 0xFF);

            // e[a][b0+m] = sum_j U[j]*Ac[j][b]
            float ex = fmaf(U3, A3.x, fmaf(U2, A2.x, fmaf(U1, A1.x, U0 * A0.x)));
            float ey = fmaf(U3, A3.y, fmaf(U2, A2.y, fmaf(U1, A1.y, U0 * A0.y)));
            float ez = fmaf(U3, A3.z, fmaf(U2, A2.z, fmaf(U1, A1.z, U0 * A0.z)));
            float ew = fmaf(U3, A3.w, fmaf(U2, A2.w, fmaf(U1, A1.w, U0 * A0.w)));

            float glf  = (lrv + lcv) * lfmask;
            float part = fmaf(glf, glf, fmaf(ew, ew, fmaf(ez, ez, fmaf(ey, ey, ex * ex))));
            float tot  = wave_sum64(part);
            float invr = __builtin_amdgcn_rcpf(__builtin_amdgcn_sqrtf(tot) + 1.f);

            ax = fmaf(ex, invr, ax); ay = fmaf(ey, invr, ay);
            az = fmaf(ez, invr, az); aw = fmaf(ew, invr, aw);
            sgeo = fmaf(glf, invr, sgeo);
            invs += invr;
            sp = fmaf(lcv, pmask, sp);

            A0 = An0; A1 = An1; A2 = An2; A3 = An3;
            cc = ccn; lcv = lcvn;
        }
    }

    // per-node sums: [0..255] radial (k = a*16+b = l*4+m), [256..264] geo,
    // [265..271] zero, [272] invs, [273..275] pooled sums
    *(float4*)&S[w][l * 4] = make_float4(ax, ay, az, aw);
    if (l < 9)       S[w][256 + l] = sgeo;
    else if (l < 16) S[w][256 + l] = 0.f;
    if (l == 16)     S[w][272] = invs;
    if (l >= 12 && l < 15) S[w][273 + (l - 12)] = sp;
    // S is wave-private: program-order DS deps suffice, no barrier

    float invsum = S[w][272];
    float acc = bvec[l] * invsum;
    const float4* WK4 = (const float4*)wk;
    #pragma unroll 4
    for (int kb = 0; kb < NKB; ++kb) {
        float4 wv = WK4[kb * 64 + l];
        float4 sv = *(const float4*)&S[w][kb * 4];
        acc += wv.x * sv.x + wv.y * sv.y + wv.z * sv.z + wv.w * sv.w;
    }
    out[(size_t)n * OUTC + l] = acc;

    float cntv = (float)deg;
    float invc = __builtin_amdgcn_rcpf(fmaxf(cntv, 1.f));
    if (l < 12) {
        int x = l % 3;
        out[(size_t)n * OUTC + 64 + l] = (cntv * coord[(size_t)n * 12 + l] - S[w][273 + x]) * invc;
    }
}

extern "C" void kernel_launch(void* const* d_in, const int* in_sizes, int n_in,
                              void* d_out, int out_size, void* d_ws, size_t ws_size,
                              hipStream_t stream) {
    const float* coord = (const float*)d_in[0];
    const float* attr  = (const float*)d_in[1];
    const float* cw    = (const float*)d_in[2];
    const float* W     = (const float*)d_in[3];
    const float* bvec  = (const float*)d_in[4];
    const int*   row   = (const int*)d_in[5];
    const int*   col   = (const int*)d_in[6];
    float* out = (float*)d_out;
    float* ws  = (float*)d_ws;
    int E = in_sizes[5];

    float* ccwp = ws + CCW_OFF;
    float* lfp  = ws + LFP_OFF;
    float* wk   = ws + WK_OFF;
    int* counts = (int*)(ws + CNT_OFF);
    int* cursor = (int*)(ws + CUR_OFF);
    int* offs   = (int*)(ws + OFFS_OFF);
    int* perm   = (int*)(ws + PERM_OFF);
    int* ecol   = (int*)(ws + ECOL_OFF);

    hipMemsetAsync(counts, 0, (NN + 4) * sizeof(int), stream);   // counts + cursor
    prep_hist_kernel<<<(E + 255) / 256, 256, 0, stream>>>(
        coord, cw, W, row, ccwp, lfp, wk, counts, perm, E);
    scanalloc_kernel<<<NB, 256, 0, stream>>>(counts, cursor, offs);
    scatter_kernel<<<(E + 255) / 256, 256, 0, stream>>>(row, col, offs, perm, ecol, E);
    edge_kernel<<<NN / 4, 256, 0, stream>>>(coord, attr, bvec, ccwp, lfp, wk,
                                            offs, counts, ecol, out);
}

// Round 10
// 292.982 us; speedup vs baseline: 1.2073x; 1.2073x over previous
//
#include <hip/hip_runtime.h>
#include <math.h>

// Problem constants (fixed by the reference)
#define NN 50000
#define EDG 800000
#define OUTC 76
#define NKB 68          // 272/4 k-blocks in the packed-W projection
#define NB  196         // scan blocks = ceil(NN/256)

// ws float offsets
#define CCW_OFF  0                     // NN*16  packed (xyz,cw) per channel
#define LFP_OFF  (CCW_OFF + NN*16)     // NN*16  [lf*9, 0,0,0, pooled*3, 0]
#define WK_OFF   (LFP_OFF + NN*16)     // NKB*256 k-major packed W
#define CNT_OFF  (WK_OFF + NKB*256)    // NN ints
#define CUR_OFF  (CNT_OFF + NN)        // 1 int cursor (+3 pad)
#define OFFS_OFF (CUR_OFF + 4)         // NN ints
#define PERM_OFF (OFFS_OFF + NN)       // EDG ints
#define ECOL_OFF (PERM_OFF + EDG)      // EDG ints

// ---------------- fused prep (nodes + WK) + histogram ----------------
__global__ void prep_hist_kernel(const float* __restrict__ coord,
                                 const float* __restrict__ cw,
                                 const float* __restrict__ W,
                                 const int* __restrict__ row,
                                 float* __restrict__ ccwp,
                                 float* __restrict__ lfp,
                                 float* __restrict__ wk,
                                 int* __restrict__ counts,
                                 int* __restrict__ perm, int E) {
    int t = blockIdx.x * blockDim.x + threadIdx.x;

    if (t < E) perm[t] = atomicAdd(&counts[row[t]], 1);

    if (t < NKB * 64) {
        int kb = t >> 6, d = t & 63;
        float tmp[4];
        #pragma unroll
        for (int km = 0; km < 4; ++km) {
            int k = kb * 4 + km;
            int kcol = (k < 256) ? k : ((k < 265) ? k + 8 : -1);
            tmp[km] = (kcol >= 0) ? W[d * 273 + kcol] : 0.f;
        }
        ((float4*)wk)[t] = make_float4(tmp[0], tmp[1], tmp[2], tmp[3]);
    }

    if (t >= NN) return;
    const float* cp = coord + (size_t)t * 12;
    float c0x = cp[0], c0y = cp[1], c0z = cp[2];
    float c1x = cp[3], c1y = cp[4], c1z = cp[5];
    float c2x = cp[6], c2y = cp[7], c2z = cp[8];
    float c3x = cp[9], c3y = cp[10], c3z = cp[11];
    const float* wv = cw + (size_t)t * 4;
    float w0 = wv[0], w1 = wv[1], w2 = wv[2], w3 = wv[3];

    float* cc = ccwp + (size_t)t * 16;
    cc[0] = c0x; cc[1] = c0y; cc[2] = c0z; cc[3] = w0;
    cc[4] = c1x; cc[5] = c1y; cc[6] = c1z; cc[7] = w1;
    cc[8] = c2x; cc[9] = c2y; cc[10] = c2z; cc[11] = w2;
    cc[12] = c3x; cc[13] = c3y; cc[14] = c3z; cc[15] = w3;

    float xx = c1x - c0x, xy = c1y - c0y, xz = c1z - c0z;
    float invx = 1.0f / (sqrtf(xx * xx + xy * xy + xz * xz) + 1e-8f);
    xx *= invx; xy *= invx; xz *= invx;
    float tx = c2x - c0x, ty = c2y - c0y, tz = c2z - c0z;
    float dp = tx * xx + ty * xy + tz * xz;
    float yx = tx - dp * xx, yy = ty - dp * xy, yz = tz - dp * xz;
    float invy = 1.0f / (sqrtf(yx * yx + yy * yy + yz * yz) + 1e-8f);
    yx *= invy; yy *= invy; yz *= invy;
    float zx = xy * yz - xz * yy;
    float zy = xz * yx - xx * yz;
    float zz = xx * yy - xy * yx;

    float m0 = (w0 != 0.f) ? 1.f : 0.f;
    float m1 = (w1 != 0.f) ? 1.f : 0.f;
    float m2 = (w2 != 0.f) ? 1.f : 0.f;
    float m3 = (w3 != 0.f) ? 1.f : 0.f;
    float cs = m0 + m1 + m2 + m3;      // ref divides directly (no clamp)
    float px = (c0x * m0 + c1x * m1 + c2x * m2 + c3x * m3) / cs;
    float py = (c0y * m0 + c1y * m1 + c2y * m2 + c3y * m3) / cs;
    float pz = (c0z * m0 + c1z * m1 + c2z * m2 + c3z * m3) / cs;

    float* lp = lfp + (size_t)t * 16;
    lp[0] = xx; lp[1] = yx; lp[2] = zx;
    lp[3] = xy; lp[4] = yy; lp[5] = zy;
    lp[6] = xz; lp[7] = yz; lp[8] = zz;
    lp[9] = 0.f; lp[10] = 0.f; lp[11] = 0.f;
    lp[12] = px; lp[13] = py; lp[14] = pz; lp[15] = 0.f;
}

// ---------------- segment allocation: block scan + one atomic ----------------
__global__ void scanalloc_kernel(const int* __restrict__ counts,
                                 int* __restrict__ cursor,
                                 int* __restrict__ offs) {
    int t = blockIdx.x * 256 + threadIdx.x;
    int v = (t < NN) ? counts[t] : 0;
    int lane = threadIdx.x & 63, wid = threadIdx.x >> 6;
    int x = v;
    #pragma unroll
    for (int d = 1; d < 64; d <<= 1) {
        int u = __shfl_up(x, d);
        x += (lane >= d) ? u : 0;
    }
    __shared__ int wtot[4];
    __shared__ int sbase;
    if (lane == 63) wtot[wid] = x;
    __syncthreads();
    if (threadIdx.x == 0)
        sbase = atomicAdd(cursor, wtot[0] + wtot[1] + wtot[2] + wtot[3]);
    __syncthreads();
    int wbase = 0;
    for (int i = 0; i < wid; ++i) wbase += wtot[i];
    if (t < NN) offs[t] = sbase + wbase + x - v;
}

__global__ void scatter_kernel(const int* __restrict__ row, const int* __restrict__ col,
                               const int* __restrict__ offs, const int* __restrict__ perm,
                               int* __restrict__ ecol, int E) {
    int e = blockIdx.x * blockDim.x + threadIdx.x;
    if (e >= E) return;
    ecol[offs[row[e]] + perm[e]] = col[e];
}

// ---------------- DPP wave-64 sum ----------------
__device__ __forceinline__ float wave_sum64(float x) {
    float v = x, t;
    t = __int_as_float(__builtin_amdgcn_update_dpp(0, __float_as_int(v), 0x111, 0xf, 0xf, true)); v += t;
    t = __int_as_float(__builtin_amdgcn_update_dpp(0, __float_as_int(v), 0x112, 0xf, 0xf, true)); v += t;
    t = __int_as_float(__builtin_amdgcn_update_dpp(0, __float_as_int(v), 0x114, 0xf, 0xf, true)); v += t;
    t = __int_as_float(__builtin_amdgcn_update_dpp(0, __float_as_int(v), 0x118, 0xf, 0xf, true)); v += t;
    t = __int_as_float(__builtin_amdgcn_update_dpp(0, __float_as_int(v), 0x142, 0xa, 0xf, true)); v += t;
    t = __int_as_float(__builtin_amdgcn_update_dpp(0, __float_as_int(v), 0x143, 0xc, 0xf, true)); v += t;
    return __int_as_float(__builtin_amdgcn_readlane(__float_as_int(v), 63));
}

// DPP helpers (VALU pipe only)
#define DPP(x, pat) __int_as_float(__builtin_amdgcn_update_dpp(0, __float_as_int(x), pat, 0xf, 0xf, true))

// ---------------- main: one wave per node ----------------
__global__ __launch_bounds__(256) void edge_kernel(
    const float* __restrict__ coord, const float* __restrict__ attr,
    const float* __restrict__ bvec,
    const float* __restrict__ ccw, const float* __restrict__ lfp,
    const float* __restrict__ wk,
    const int* __restrict__ offs, const int* __restrict__ counts,
    const int* __restrict__ ecol,
    float* __restrict__ out) {
    __shared__ float Acbuf[4][64];
    __shared__ float S[4][280];

    const int w = threadIdx.x >> 6;
    const int l = threadIdx.x & 63;
    const int l15 = l & 15;
    const int n = blockIdx.x * 4 + w;

    const int st = offs[n];
    const int deg = counts[n];
    const int en = st + deg;
    const int b0 = (l & 3) * 4;
    const int i4 = (l >> 2) & 3;
    const int j4 = l & 3;
    const int a  = l >> 2;

    // Ar coefficients pre-permuted for the row_ror ladder.
    // DPP convention (empirically fixed by wave_sum64's row_shr): dest[i]=src[i-n].
    // So row_ror:4k delivers M[(i4-k)&3][j4]; coefficient must be Ar[(i4-k)&3][a].
    const float Br0 = attr[(size_t)n * 64 + (size_t)(((i4 + 0) & 3) * 16) + a];
    const float Br1 = attr[(size_t)n * 64 + (size_t)(((i4 + 3) & 3) * 16) + a];  // (i4-1)&3
    const float Br2 = attr[(size_t)n * 64 + (size_t)(((i4 + 2) & 3) * 16) + a];  // (i4-2)&3
    const float Br3 = attr[(size_t)n * 64 + (size_t)(((i4 + 1) & 3) * 16) + a];  // (i4-3)&3
    const float4 cown = ((const float4*)ccw)[n * 4 + i4];
    const float crx = cown.x, cry = cown.y, crz = cown.z, cwr = cown.w;
    const float lrv = lfp[(size_t)n * 16 + l15];
    const float lfmask = (l < 9) ? 1.f : 0.f;
    const float pmask  = (l >= 12 && l < 15) ? 1.f : 0.f;

    float ax = 0.f, ay = 0.f, az = 0.f, aw = 0.f;
    float sgeo = 0.f, invs = 0.f, sp = 0.f;

    const float4* CCW4 = (const float4*)ccw;

    for (int base = st; base < en; base += 64) {
        int bcnt = en - base; bcnt = bcnt > 64 ? 64 : bcnt;
        int idx = base + (l < bcnt ? l : bcnt - 1);
        int cvec = ecol[idx];

        int c = __builtin_amdgcn_readlane(cvec, 0);
        float4 cc  = CCW4[c * 4 + j4];
        float  acv = attr[(size_t)c * 64 + l];
        float  lcv = lfp[c * 16 + l15];

        for (int k = 0; k < bcnt; ++k) {
            // stage current attr row into LDS (wait hidden under VALU below)
            Acbuf[w][l] = acv;

            // prefetch next edge (SGPR base + const voffset)
            int kn = (k + 1 < bcnt) ? k + 1 : k;
            int c2 = __builtin_amdgcn_readlane(cvec, kn);
            float4 cc_n  = CCW4[c2 * 4 + j4];
            float  ac_n  = attr[(size_t)c2 * 64 + l];
            float  lcv_n = lfp[c2 * 16 + l15];

            // distance entry M[i4][j4] (full 4x4 replica in each 16-lane row)
            float dx = crx - cc.x, dy = cry - cc.y, dz = crz - cc.z;
            float m = __builtin_amdgcn_sqrtf(fmaf(dx, dx, fmaf(dy, dy, dz * dz))) * cwr * cc.w;

            // U[j4][a] via row_ror ladder (VALU pipe): mr_{4k} = M[(i4-k)&3][j4]
            float mr4  = DPP(m, 0x124);   // row_ror:4
            float mr8  = DPP(m, 0x128);   // row_ror:8
            float mr12 = DPP(m, 0x12C);   // row_ror:12
            float Uo = fmaf(Br3, mr12, fmaf(Br2, mr8, fmaf(Br1, mr4, Br0 * m)));

            // quad q=a holds U[0..3][a] at quad-lanes 0..3 -> quad_perm broadcast
            float U0 = DPP(Uo, 0x00);     // quad_perm [0,0,0,0]
            float U1 = DPP(Uo, 0x55);     // quad_perm [1,1,1,1]
            float U2 = DPP(Uo, 0xAA);     // quad_perm [2,2,2,2]
            float U3 = DPP(Uo, 0xFF);     // quad_perm [3,3,3,3]

            float4 A0 = *(const float4*)&Acbuf[w][b0];
            float4 A1 = *(const float4*)&Acbuf[w][16 + b0];
            float4 A2 = *(const float4*)&Acbuf[w][32 + b0];
            float4 A3 = *(const float4*)&Acbuf[w][48 + b0];
            float ex = fmaf(U3, A3.x, fmaf(U2, A2.x, fmaf(U1, A1.x, U0 * A0.x)));
            float ey = fmaf(U3, A3.y, fmaf(U2, A2.y, fmaf(U1, A1.y, U0 * A0.y)));
            float ez = fmaf(U3, A3.z, fmaf(U2, A2.z, fmaf(U1, A1.z, U0 * A0.z)));
            float ew = fmaf(U3, A3.w, fmaf(U2, A2.w, fmaf(U1, A1.w, U0 * A0.w)));

            float glf  = (lrv + lcv) * lfmask;
            float part = fmaf(glf, glf, fmaf(ew, ew, fmaf(ez, ez, fmaf(ey, ey, ex * ex))));
            float tot  = wave_sum64(part);
            float invr = __builtin_amdgcn_rcpf(__builtin_amdgcn_sqrtf(tot) + 1.f);

            ax = fmaf(ex, invr, ax); ay = fmaf(ey, invr, ay);
            az = fmaf(ez, invr, az); aw = fmaf(ew, invr, aw);
            sgeo = fmaf(glf, invr, sgeo);
            invs += invr;
            sp = fmaf(lcv, pmask, sp);

            cc = cc_n; acv = ac_n; lcv = lcv_n;
        }
    }

    // per-node sums: [0..255] radial (k = a*16+b = l*4+m), [256..264] geo,
    // [265..271] zero, [272] invs, [273..275] pooled sums
    *(float4*)&S[w][l * 4] = make_float4(ax, ay, az, aw);
    if (l < 9)       S[w][256 + l] = sgeo;
    else if (l < 16) S[w][256 + l] = 0.f;
    if (l == 16)     S[w][272] = invs;
    if (l >= 12 && l < 15) S[w][273 + (l - 12)] = sp;
    // S is wave-private: program-order DS deps suffice, no barrier

    float invsum = S[w][272];
    float acc = bvec[l] * invsum;
    const float4* WK4 = (const float4*)wk;
    #pragma unroll 4
    for (int kb = 0; kb < NKB; ++kb) {
        float4 wv = WK4[kb * 64 + l];
        float4 sv = *(const float4*)&S[w][kb * 4];
        acc += wv.x * sv.x + wv.y * sv.y + wv.z * sv.z + wv.w * sv.w;
    }
    out[(size_t)n * OUTC + l] = acc;

    float cntv = (float)deg;
    float invc = __builtin_amdgcn_rcpf(fmaxf(cntv, 1.f));
    if (l < 12) {
        int x = l % 3;
        out[(size_t)n * OUTC + 64 + l] = (cntv * coord[(size_t)n * 12 + l] - S[w][273 + x]) * invc;
    }
}

extern "C" void kernel_launch(void* const* d_in, const int* in_sizes, int n_in,
                              void* d_out, int out_size, void* d_ws, size_t ws_size,
                              hipStream_t stream) {
    const float* coord = (const float*)d_in[0];
    const float* attr  = (const float*)d_in[1];
    const float* cw    = (const float*)d_in[2];
    const float* W     = (const float*)d_in[3];
    const float* bvec  = (const float*)d_in[4];
    const int*   row   = (const int*)d_in[5];
    const int*   col   = (const int*)d_in[6];
    float* out = (float*)d_out;
    float* ws  = (float*)d_ws;
    int E = in_sizes[5];

    float* ccwp = ws + CCW_OFF;
    float* lfp  = ws + LFP_OFF;
    float* wk   = ws + WK_OFF;
    int* counts = (int*)(ws + CNT_OFF);
    int* cursor = (int*)(ws + CUR_OFF);
    int* offs   = (int*)(ws + OFFS_OFF);
    int* perm   = (int*)(ws + PERM_OFF);
    int* ecol   = (int*)(ws + ECOL_OFF);

    hipMemsetAsync(counts, 0, (NN + 4) * sizeof(int), stream);   // counts + cursor
    prep_hist_kernel<<<(E + 255) / 256, 256, 0, stream>>>(
        coord, cw, W, row, ccwp, lfp, wk, counts, perm, E);
    scanalloc_kernel<<<NB, 256, 0, stream>>>(counts, cursor, offs);
    scatter_kernel<<<(E + 255) / 256, 256, 0, stream>>>(row, col, offs, perm, ecol, E);
    edge_kernel<<<NN / 4, 256, 0, stream>>>(coord, attr, bvec, ccwp, lfp, wk,
                                            offs, counts, ecol, out);
}

// Round 11
// 291.501 us; speedup vs baseline: 1.2134x; 1.0051x over previous
//
#include <hip/hip_runtime.h>
#include <math.h>

// Problem constants (fixed by the reference)
#define NN 50000
#define EDG 800000
#define OUTC 76
#define NKB 68          // 272/4 k-blocks in the packed-W projection
#define NB  196         // scan blocks = ceil(NN/256)
#define CAP 64          // bucket capacity (max degree ~38 for this graph; P(>=64)~1e-15)

// ws float offsets (common prefix)
#define CCW_OFF  0                     // NN*16  packed (xyz,cw) per channel
#define LFP_OFF  (CCW_OFF + NN*16)     // NN*16  [lf*9, 0,0,0, pooled*3, 0]
#define WK_OFF   (LFP_OFF + NN*16)     // NKB*256 k-major packed W
#define CNT_OFF  (WK_OFF + NKB*256)    // NN ints
#define CUR_OFF  (CNT_OFF + NN)        // 1 int cursor (+3 pad)
#define OFFS_OFF (CUR_OFF + 4)         // NN ints (+4 pad)
#define TAIL_OFF (OFFS_OFF + NN + 4)
// CSR tail:    PERM (EDG) + ECOL (EDG)          -> 13.3 MB total
// bucket tail: ECOLB (NN*CAP)                   -> 19.7 MB total
#define BUCKET_FLOATS ((size_t)TAIL_OFF + (size_t)NN * CAP)

// ---------------- fused prep (nodes + WK) + histogram (+bucket scatter) -----
__global__ void prep_kernel(const float* __restrict__ coord,
                            const float* __restrict__ cw,
                            const float* __restrict__ W,
                            const int* __restrict__ row,
                            const int* __restrict__ col,
                            float* __restrict__ ccwp,
                            float* __restrict__ lfp,
                            float* __restrict__ wk,
                            int* __restrict__ counts,
                            int* __restrict__ perm,      // CSR mode
                            int* __restrict__ ecolb,     // bucket mode
                            int* __restrict__ offs,      // bucket mode: n*CAP
                            int E, int bucket) {
    int t = blockIdx.x * blockDim.x + threadIdx.x;

    if (t < E) {
        int r = row[t];
        int slot = atomicAdd(&counts[r], 1);
        if (bucket) ecolb[r * CAP + slot] = col[t];
        else        perm[t] = slot;
    }

    if (t < NKB * 64) {
        int kb = t >> 6, d = t & 63;
        float tmp[4];
        #pragma unroll
        for (int km = 0; km < 4; ++km) {
            int k = kb * 4 + km;
            int kcol = (k < 256) ? k : ((k < 265) ? k + 8 : -1);
            tmp[km] = (kcol >= 0) ? W[d * 273 + kcol] : 0.f;
        }
        ((float4*)wk)[t] = make_float4(tmp[0], tmp[1], tmp[2], tmp[3]);
    }

    if (t >= NN) return;
    if (bucket) offs[t] = t * CAP;

    const float* cp = coord + (size_t)t * 12;
    float c0x = cp[0], c0y = cp[1], c0z = cp[2];
    float c1x = cp[3], c1y = cp[4], c1z = cp[5];
    float c2x = cp[6], c2y = cp[7], c2z = cp[8];
    float c3x = cp[9], c3y = cp[10], c3z = cp[11];
    const float* wv = cw + (size_t)t * 4;
    float w0 = wv[0], w1 = wv[1], w2 = wv[2], w3 = wv[3];

    float* cc = ccwp + (size_t)t * 16;
    cc[0] = c0x; cc[1] = c0y; cc[2] = c0z; cc[3] = w0;
    cc[4] = c1x; cc[5] = c1y; cc[6] = c1z; cc[7] = w1;
    cc[8] = c2x; cc[9] = c2y; cc[10] = c2z; cc[11] = w2;
    cc[12] = c3x; cc[13] = c3y; cc[14] = c3z; cc[15] = w3;

    float xx = c1x - c0x, xy = c1y - c0y, xz = c1z - c0z;
    float invx = 1.0f / (sqrtf(xx * xx + xy * xy + xz * xz) + 1e-8f);
    xx *= invx; xy *= invx; xz *= invx;
    float tx = c2x - c0x, ty = c2y - c0y, tz = c2z - c0z;
    float dp = tx * xx + ty * xy + tz * xz;
    float yx = tx - dp * xx, yy = ty - dp * xy, yz = tz - dp * xz;
    float invy = 1.0f / (sqrtf(yx * yx + yy * yy + yz * yz) + 1e-8f);
    yx *= invy; yy *= invy; yz *= invy;
    float zx = xy * yz - xz * yy;
    float zy = xz * yx - xx * yz;
    float zz = xx * yy - xy * yx;

    float m0 = (w0 != 0.f) ? 1.f : 0.f;
    float m1 = (w1 != 0.f) ? 1.f : 0.f;
    float m2 = (w2 != 0.f) ? 1.f : 0.f;
    float m3 = (w3 != 0.f) ? 1.f : 0.f;
    float cs = m0 + m1 + m2 + m3;      // ref divides directly (no clamp)
    float px = (c0x * m0 + c1x * m1 + c2x * m2 + c3x * m3) / cs;
    float py = (c0y * m0 + c1y * m1 + c2y * m2 + c3y * m3) / cs;
    float pz = (c0z * m0 + c1z * m1 + c2z * m2 + c3z * m3) / cs;

    float* lp = lfp + (size_t)t * 16;
    lp[0] = xx; lp[1] = yx; lp[2] = zx;
    lp[3] = xy; lp[4] = yy; lp[5] = zy;
    lp[6] = xz; lp[7] = yz; lp[8] = zz;
    lp[9] = 0.f; lp[10] = 0.f; lp[11] = 0.f;
    lp[12] = px; lp[13] = py; lp[14] = pz; lp[15] = 0.f;
}

// ---------------- CSR fallback: segment allocation + scatter ----------------
__global__ void scanalloc_kernel(const int* __restrict__ counts,
                                 int* __restrict__ cursor,
                                 int* __restrict__ offs) {
    int t = blockIdx.x * 256 + threadIdx.x;
    int v = (t < NN) ? counts[t] : 0;
    int lane = threadIdx.x & 63, wid = threadIdx.x >> 6;
    int x = v;
    #pragma unroll
    for (int d = 1; d < 64; d <<= 1) {
        int u = __shfl_up(x, d);
        x += (lane >= d) ? u : 0;
    }
    __shared__ int wtot[4];
    __shared__ int sbase;
    if (lane == 63) wtot[wid] = x;
    __syncthreads();
    if (threadIdx.x == 0)
        sbase = atomicAdd(cursor, wtot[0] + wtot[1] + wtot[2] + wtot[3]);
    __syncthreads();
    int wbase = 0;
    for (int i = 0; i < wid; ++i) wbase += wtot[i];
    if (t < NN) offs[t] = sbase + wbase + x - v;
}

__global__ void scatter_kernel(const int* __restrict__ row, const int* __restrict__ col,
                               const int* __restrict__ offs, const int* __restrict__ perm,
                               int* __restrict__ ecol, int E) {
    int e = blockIdx.x * blockDim.x + threadIdx.x;
    if (e >= E) return;
    ecol[offs[row[e]] + perm[e]] = col[e];
}

// ---------------- DPP wave-64 sum ----------------
__device__ __forceinline__ float wave_sum64(float x) {
    float v = x, t;
    t = __int_as_float(__builtin_amdgcn_update_dpp(0, __float_as_int(v), 0x111, 0xf, 0xf, true)); v += t;
    t = __int_as_float(__builtin_amdgcn_update_dpp(0, __float_as_int(v), 0x112, 0xf, 0xf, true)); v += t;
    t = __int_as_float(__builtin_amdgcn_update_dpp(0, __float_as_int(v), 0x114, 0xf, 0xf, true)); v += t;
    t = __int_as_float(__builtin_amdgcn_update_dpp(0, __float_as_int(v), 0x118, 0xf, 0xf, true)); v += t;
    t = __int_as_float(__builtin_amdgcn_update_dpp(0, __float_as_int(v), 0x142, 0xa, 0xf, true)); v += t;
    t = __int_as_float(__builtin_amdgcn_update_dpp(0, __float_as_int(v), 0x143, 0xc, 0xf, true)); v += t;
    return __int_as_float(__builtin_amdgcn_readlane(__float_as_int(v), 63));
}

// DPP helpers (VALU pipe only)
#define DPP(x, pat) __int_as_float(__builtin_amdgcn_update_dpp(0, __float_as_int(x), pat, 0xf, 0xf, true))

// ---------------- main: one wave per node ----------------
__global__ __launch_bounds__(256) void edge_kernel(
    const float* __restrict__ coord, const float* __restrict__ attr,
    const float* __restrict__ bvec,
    const float* __restrict__ ccw, const float* __restrict__ lfp,
    const float* __restrict__ wk,
    const int* __restrict__ offs, const int* __restrict__ counts,
    const int* __restrict__ ecol,
    float* __restrict__ out) {
    __shared__ float Acbuf[4][64];
    __shared__ float S[4][280];

    const int w = threadIdx.x >> 6;
    const int l = threadIdx.x & 63;
    const int l15 = l & 15;
    const int n = blockIdx.x * 4 + w;

    const int st = offs[n];
    const int deg = counts[n];
    const int en = st + deg;
    const int b0 = (l & 3) * 4;
    const int i4 = (l >> 2) & 3;
    const int j4 = l & 3;
    const int a  = l >> 2;

    // Ar coefficients pre-permuted for the row_ror ladder.
    // DPP convention (empirically fixed by wave_sum64's row_shr): dest[i]=src[i-n].
    // So row_ror:4k delivers M[(i4-k)&3][j4]; coefficient must be Ar[(i4-k)&3][a].
    const float Br0 = attr[(size_t)n * 64 + (size_t)(((i4 + 0) & 3) * 16) + a];
    const float Br1 = attr[(size_t)n * 64 + (size_t)(((i4 + 3) & 3) * 16) + a];  // (i4-1)&3
    const float Br2 = attr[(size_t)n * 64 + (size_t)(((i4 + 2) & 3) * 16) + a];  // (i4-2)&3
    const float Br3 = attr[(size_t)n * 64 + (size_t)(((i4 + 1) & 3) * 16) + a];  // (i4-3)&3
    const float4 cown = ((const float4*)ccw)[n * 4 + i4];
    const float crx = cown.x, cry = cown.y, crz = cown.z, cwr = cown.w;
    const float lrv = lfp[(size_t)n * 16 + l15];
    const float lfmask = (l < 9) ? 1.f : 0.f;
    const float pmask  = (l >= 12 && l < 15) ? 1.f : 0.f;

    float ax = 0.f, ay = 0.f, az = 0.f, aw = 0.f;
    float sgeo = 0.f, invs = 0.f, sp = 0.f;

    const float4* CCW4 = (const float4*)ccw;

    for (int base = st; base < en; base += 64) {
        int bcnt = en - base; bcnt = bcnt > 64 ? 64 : bcnt;
        int idx = base + (l < bcnt ? l : bcnt - 1);
        int cvec = ecol[idx];

        int c = __builtin_amdgcn_readlane(cvec, 0);
        float4 cc  = CCW4[c * 4 + j4];
        float  acv = attr[(size_t)c * 64 + l];
        float  lcv = lfp[c * 16 + l15];

        #pragma unroll 2
        for (int k = 0; k < bcnt; ++k) {
            // stage current attr row into LDS (wait hidden under VALU below)
            Acbuf[w][l] = acv;

            // prefetch next edge (SGPR base + const voffset)
            int kn = (k + 1 < bcnt) ? k + 1 : k;
            int c2 = __builtin_amdgcn_readlane(cvec, kn);
            float4 cc_n  = CCW4[c2 * 4 + j4];
            float  ac_n  = attr[(size_t)c2 * 64 + l];
            float  lcv_n = lfp[c2 * 16 + l15];

            // distance entry M[i4][j4] (full 4x4 replica in each 16-lane row)
            float dx = crx - cc.x, dy = cry - cc.y, dz = crz - cc.z;
            float m = __builtin_amdgcn_sqrtf(fmaf(dx, dx, fmaf(dy, dy, dz * dz))) * cwr * cc.w;

            // U[j4][a] via row_ror ladder (VALU pipe): mr_{4k} = M[(i4-k)&3][j4]
            float mr4  = DPP(m, 0x124);   // row_ror:4
            float mr8  = DPP(m, 0x128);   // row_ror:8
            float mr12 = DPP(m, 0x12C);   // row_ror:12
            float Uo = fmaf(Br3, mr12, fmaf(Br2, mr8, fmaf(Br1, mr4, Br0 * m)));

            // quad q=a holds U[0..3][a] at quad-lanes 0..3 -> quad_perm broadcast
            float U0 = DPP(Uo, 0x00);     // quad_perm [0,0,0,0]
            float U1 = DPP(Uo, 0x55);     // quad_perm [1,1,1,1]
            float U2 = DPP(Uo, 0xAA);     // quad_perm [2,2,2,2]
            float U3 = DPP(Uo, 0xFF);     // quad_perm [3,3,3,3]

            float4 A0 = *(const float4*)&Acbuf[w][b0];
            float4 A1 = *(const float4*)&Acbuf[w][16 + b0];
            float4 A2 = *(const float4*)&Acbuf[w][32 + b0];
            float4 A3 = *(const float4*)&Acbuf[w][48 + b0];
            float ex = fmaf(U3, A3.x, fmaf(U2, A2.x, fmaf(U1, A1.x, U0 * A0.x)));
            float ey = fmaf(U3, A3.y, fmaf(U2, A2.y, fmaf(U1, A1.y, U0 * A0.y)));
            float ez = fmaf(U3, A3.z, fmaf(U2, A2.z, fmaf(U1, A1.z, U0 * A0.z)));
            float ew = fmaf(U3, A3.w, fmaf(U2, A2.w, fmaf(U1, A1.w, U0 * A0.w)));

            float glf  = (lrv + lcv) * lfmask;
            float part = fmaf(glf, glf, fmaf(ew, ew, fmaf(ez, ez, fmaf(ey, ey, ex * ex))));
            float tot  = wave_sum64(part);
            float invr = __builtin_amdgcn_rcpf(__builtin_amdgcn_sqrtf(tot) + 1.f);

            ax = fmaf(ex, invr, ax); ay = fmaf(ey, invr, ay);
            az = fmaf(ez, invr, az); aw = fmaf(ew, invr, aw);
            sgeo = fmaf(glf, invr, sgeo);
            invs += invr;
            sp = fmaf(lcv, pmask, sp);

            cc = cc_n; acv = ac_n; lcv = lcv_n;
        }
    }

    // per-node sums: [0..255] radial (k = a*16+b = l*4+m), [256..264] geo,
    // [265..271] zero, [272] invs, [273..275] pooled sums
    *(float4*)&S[w][l * 4] = make_float4(ax, ay, az, aw);
    if (l < 9)       S[w][256 + l] = sgeo;
    else if (l < 16) S[w][256 + l] = 0.f;
    if (l == 16)     S[w][272] = invs;
    if (l >= 12 && l < 15) S[w][273 + (l - 12)] = sp;
    // S is wave-private: program-order DS deps suffice, no barrier

    float invsum = S[w][272];
    float acc = bvec[l] * invsum;
    const float4* WK4 = (const float4*)wk;
    #pragma unroll 4
    for (int kb = 0; kb < NKB; ++kb) {
        float4 wv = WK4[kb * 64 + l];
        float4 sv = *(const float4*)&S[w][kb * 4];
        acc += wv.x * sv.x + wv.y * sv.y + wv.z * sv.z + wv.w * sv.w;
    }
    out[(size_t)n * OUTC + l] = acc;

    float cntv = (float)deg;
    float invc = __builtin_amdgcn_rcpf(fmaxf(cntv, 1.f));
    if (l < 12) {
        int x = l % 3;
        out[(size_t)n * OUTC + 64 + l] = (cntv * coord[(size_t)n * 12 + l] - S[w][273 + x]) * invc;
    }
}

extern "C" void kernel_launch(void* const* d_in, const int* in_sizes, int n_in,
                              void* d_out, int out_size, void* d_ws, size_t ws_size,
                              hipStream_t stream) {
    const float* coord = (const float*)d_in[0];
    const float* attr  = (const float*)d_in[1];
    const float* cw    = (const float*)d_in[2];
    const float* W     = (const float*)d_in[3];
    const float* bvec  = (const float*)d_in[4];
    const int*   row   = (const int*)d_in[5];
    const int*   col   = (const int*)d_in[6];
    float* out = (float*)d_out;
    float* ws  = (float*)d_ws;
    int E = in_sizes[5];

    float* ccwp = ws + CCW_OFF;
    float* lfp  = ws + LFP_OFF;
    float* wk   = ws + WK_OFF;
    int* counts = (int*)(ws + CNT_OFF);
    int* cursor = (int*)(ws + CUR_OFF);
    int* offs   = (int*)(ws + OFFS_OFF);
    int* tail   = (int*)(ws + TAIL_OFF);

    // deterministic across calls (ws_size fixed) -> graph-safe
    const int bucket = (ws_size >= BUCKET_FLOATS * sizeof(float)) ? 1 : 0;

    hipMemsetAsync(counts, 0, (NN + 4) * sizeof(int), stream);   // counts + cursor

    if (bucket) {
        int* ecolb = tail;                       // NN*CAP
        prep_kernel<<<(E + 255) / 256, 256, 0, stream>>>(
            coord, cw, W, row, col, ccwp, lfp, wk, counts,
            /*perm*/nullptr, ecolb, offs, E, 1);
        edge_kernel<<<NN / 4, 256, 0, stream>>>(coord, attr, bvec, ccwp, lfp, wk,
                                                offs, counts, ecolb, out);
    } else {
        int* perm = tail;                        // EDG
        int* ecol = tail + EDG;                  // EDG
        prep_kernel<<<(E + 255) / 256, 256, 0, stream>>>(
            coord, cw, W, row, col, ccwp, lfp, wk, counts,
            perm, /*ecolb*/nullptr, offs, E, 0);
        scanalloc_kernel<<<NB, 256, 0, stream>>>(counts, cursor, offs);
        scatter_kernel<<<(E + 255) / 256, 256, 0, stream>>>(row, col, offs, perm, ecol, E);
        edge_kernel<<<NN / 4, 256, 0, stream>>>(coord, attr, bvec, ccwp, lfp, wk,
                                                offs, counts, ecol, out);
    }
}

// Round 12
// 290.449 us; speedup vs baseline: 1.2178x; 1.0036x over previous
//
#include <hip/hip_runtime.h>
#include <math.h>

// Problem constants (fixed by the reference)
#define NN 50000
#define EDG 800000
#define OUTC 76
#define NKB 68          // 272/4 k-blocks in the packed-W projection
#define NB  196         // scan blocks = ceil(NN/256)
#define CAP 64          // bucket capacity (max degree ~38 for this graph)

// ws float offsets (common prefix)
#define CCW_OFF  0                     // NN*16  packed (xyz,cw) per channel
#define LFP_OFF  (CCW_OFF + NN*16)     // NN*16  [lf*9, 0,0,0, pooled*3, 0]
#define WK_OFF   (LFP_OFF + NN*16)     // NKB*256 k-major packed W
#define CNT_OFF  (WK_OFF + NKB*256)    // NN ints
#define CUR_OFF  (CNT_OFF + NN)        // 1 int cursor (+3 pad)
#define OFFS_OFF (CUR_OFF + 4)         // NN ints (+4 pad)
#define TAIL_OFF (OFFS_OFF + NN + 4)
// CSR tail:    PERM (EDG) + ECOL (EDG)          -> 13.3 MB total
// bucket tail: ECOLB (NN*CAP)                   -> 19.7 MB total
#define BUCKET_FLOATS ((size_t)TAIL_OFF + (size_t)NN * CAP)

// ---------------- fused prep (nodes + WK) + histogram (+bucket scatter) -----
__global__ void prep_kernel(const float* __restrict__ coord,
                            const float* __restrict__ cw,
                            const float* __restrict__ W,
                            const int* __restrict__ row,
                            const int* __restrict__ col,
                            float* __restrict__ ccwp,
                            float* __restrict__ lfp,
                            float* __restrict__ wk,
                            int* __restrict__ counts,
                            int* __restrict__ perm,      // CSR mode
                            int* __restrict__ ecolb,     // bucket mode
                            int* __restrict__ offs,      // bucket mode: n*CAP
                            int E, int bucket) {
    int t = blockIdx.x * blockDim.x + threadIdx.x;

    if (t < E) {
        int r = row[t];
        int slot = atomicAdd(&counts[r], 1);
        if (bucket) ecolb[r * CAP + slot] = col[t];
        else        perm[t] = slot;
    }

    if (t < NKB * 64) {
        int kb = t >> 6, d = t & 63;
        float tmp[4];
        #pragma unroll
        for (int km = 0; km < 4; ++km) {
            int k = kb * 4 + km;
            int kcol = (k < 256) ? k : ((k < 265) ? k + 8 : -1);
            tmp[km] = (kcol >= 0) ? W[d * 273 + kcol] : 0.f;
        }
        ((float4*)wk)[t] = make_float4(tmp[0], tmp[1], tmp[2], tmp[3]);
    }

    if (t >= NN) return;
    if (bucket) offs[t] = t * CAP;

    const float* cp = coord + (size_t)t * 12;
    float c0x = cp[0], c0y = cp[1], c0z = cp[2];
    float c1x = cp[3], c1y = cp[4], c1z = cp[5];
    float c2x = cp[6], c2y = cp[7], c2z = cp[8];
    float c3x = cp[9], c3y = cp[10], c3z = cp[11];
    const float* wv = cw + (size_t)t * 4;
    float w0 = wv[0], w1 = wv[1], w2 = wv[2], w3 = wv[3];

    float* cc = ccwp + (size_t)t * 16;
    cc[0] = c0x; cc[1] = c0y; cc[2] = c0z; cc[3] = w0;
    cc[4] = c1x; cc[5] = c1y; cc[6] = c1z; cc[7] = w1;
    cc[8] = c2x; cc[9] = c2y; cc[10] = c2z; cc[11] = w2;
    cc[12] = c3x; cc[13] = c3y; cc[14] = c3z; cc[15] = w3;

    float xx = c1x - c0x, xy = c1y - c0y, xz = c1z - c0z;
    float invx = 1.0f / (sqrtf(xx * xx + xy * xy + xz * xz) + 1e-8f);
    xx *= invx; xy *= invx; xz *= invx;
    float tx = c2x - c0x, ty = c2y - c0y, tz = c2z - c0z;
    float dp = tx * xx + ty * xy + tz * xz;
    float yx = tx - dp * xx, yy = ty - dp * xy, yz = tz - dp * xz;
    float invy = 1.0f / (sqrtf(yx * yx + yy * yy + yz * yz) + 1e-8f);
    yx *= invy; yy *= invy; yz *= invy;
    float zx = xy * yz - xz * yy;
    float zy = xz * yx - xx * yz;
    float zz = xx * yy - xy * yx;

    float m0 = (w0 != 0.f) ? 1.f : 0.f;
    float m1 = (w1 != 0.f) ? 1.f : 0.f;
    float m2 = (w2 != 0.f) ? 1.f : 0.f;
    float m3 = (w3 != 0.f) ? 1.f : 0.f;
    float cs = m0 + m1 + m2 + m3;      // ref divides directly (no clamp)
    float px = (c0x * m0 + c1x * m1 + c2x * m2 + c3x * m3) / cs;
    float py = (c0y * m0 + c1y * m1 + c2y * m2 + c3y * m3) / cs;
    float pz = (c0z * m0 + c1z * m1 + c2z * m2 + c3z * m3) / cs;

    float* lp = lfp + (size_t)t * 16;
    lp[0] = xx; lp[1] = yx; lp[2] = zx;
    lp[3] = xy; lp[4] = yy; lp[5] = zy;
    lp[6] = xz; lp[7] = yz; lp[8] = zz;
    lp[9] = 0.f; lp[10] = 0.f; lp[11] = 0.f;
    lp[12] = px; lp[13] = py; lp[14] = pz; lp[15] = 0.f;
}

// ---------------- CSR fallback: segment allocation + scatter ----------------
__global__ void scanalloc_kernel(const int* __restrict__ counts,
                                 int* __restrict__ cursor,
                                 int* __restrict__ offs) {
    int t = blockIdx.x * 256 + threadIdx.x;
    int v = (t < NN) ? counts[t] : 0;
    int lane = threadIdx.x & 63, wid = threadIdx.x >> 6;
    int x = v;
    #pragma unroll
    for (int d = 1; d < 64; d <<= 1) {
        int u = __shfl_up(x, d);
        x += (lane >= d) ? u : 0;
    }
    __shared__ int wtot[4];
    __shared__ int sbase;
    if (lane == 63) wtot[wid] = x;
    __syncthreads();
    if (threadIdx.x == 0)
        sbase = atomicAdd(cursor, wtot[0] + wtot[1] + wtot[2] + wtot[3]);
    __syncthreads();
    int wbase = 0;
    for (int i = 0; i < wid; ++i) wbase += wtot[i];
    if (t < NN) offs[t] = sbase + wbase + x - v;
}

__global__ void scatter_kernel(const int* __restrict__ row, const int* __restrict__ col,
                               const int* __restrict__ offs, const int* __restrict__ perm,
                               int* __restrict__ ecol, int E) {
    int e = blockIdx.x * blockDim.x + threadIdx.x;
    if (e >= E) return;
    ecol[offs[row[e]] + perm[e]] = col[e];
}

// ---------------- DPP wave-64 sum ----------------
__device__ __forceinline__ float wave_sum64(float x) {
    float v = x, t;
    t = __int_as_float(__builtin_amdgcn_update_dpp(0, __float_as_int(v), 0x111, 0xf, 0xf, true)); v += t;
    t = __int_as_float(__builtin_amdgcn_update_dpp(0, __float_as_int(v), 0x112, 0xf, 0xf, true)); v += t;
    t = __int_as_float(__builtin_amdgcn_update_dpp(0, __float_as_int(v), 0x114, 0xf, 0xf, true)); v += t;
    t = __int_as_float(__builtin_amdgcn_update_dpp(0, __float_as_int(v), 0x118, 0xf, 0xf, true)); v += t;
    t = __int_as_float(__builtin_amdgcn_update_dpp(0, __float_as_int(v), 0x142, 0xa, 0xf, true)); v += t;
    t = __int_as_float(__builtin_amdgcn_update_dpp(0, __float_as_int(v), 0x143, 0xc, 0xf, true)); v += t;
    return __int_as_float(__builtin_amdgcn_readlane(__float_as_int(v), 63));
}

// DPP helpers (VALU pipe only)
#define DPP(x, pat) __int_as_float(__builtin_amdgcn_update_dpp(0, __float_as_int(x), pat, 0xf, 0xf, true))

// ---------------- main: one wave per node, 2-edge ILP ----------------
__global__ __launch_bounds__(256) void edge_kernel(
    const float* __restrict__ coord, const float* __restrict__ attr,
    const float* __restrict__ bvec,
    const float* __restrict__ ccw, const float* __restrict__ lfp,
    const float* __restrict__ wk,
    const int* __restrict__ offs, const int* __restrict__ counts,
    const int* __restrict__ ecol,
    float* __restrict__ out) {
    __shared__ float Acbuf[4][2][64];
    __shared__ float S[4][280];

    const int w = threadIdx.x >> 6;
    const int l = threadIdx.x & 63;
    const int l15 = l & 15;
    const int n = blockIdx.x * 4 + w;

    const int st = offs[n];
    const int deg = counts[n];
    const int en = st + deg;
    const int b0 = (l & 3) * 4;
    const int i4 = (l >> 2) & 3;
    const int j4 = l & 3;
    const int a  = l >> 2;

    // Ar coefficients pre-permuted for the row_ror ladder (dest[i]=src[i-n]).
    const float Br0 = attr[(size_t)n * 64 + (size_t)(((i4 + 0) & 3) * 16) + a];
    const float Br1 = attr[(size_t)n * 64 + (size_t)(((i4 + 3) & 3) * 16) + a];  // (i4-1)&3
    const float Br2 = attr[(size_t)n * 64 + (size_t)(((i4 + 2) & 3) * 16) + a];  // (i4-2)&3
    const float Br3 = attr[(size_t)n * 64 + (size_t)(((i4 + 1) & 3) * 16) + a];  // (i4-3)&3
    const float4 cown = ((const float4*)ccw)[n * 4 + i4];
    const float crx = cown.x, cry = cown.y, crz = cown.z, cwr = cown.w;
    const float lrv = lfp[(size_t)n * 16 + l15];
    const float lfmask = (l < 9) ? 1.f : 0.f;
    const float pmask  = (l >= 12 && l < 15) ? 1.f : 0.f;

    float ax = 0.f, ay = 0.f, az = 0.f, aw = 0.f;
    float sgeo = 0.f, invs = 0.f, sp = 0.f;

    const float4* CCW4 = (const float4*)ccw;

    // per-edge compute: chain is independent across calls -> scheduler interleaves
    auto edge_do = [&](float4 cc, const float* Ab, float lcv) {
        float dx = crx - cc.x, dy = cry - cc.y, dz = crz - cc.z;
        float m = __builtin_amdgcn_sqrtf(fmaf(dx, dx, fmaf(dy, dy, dz * dz))) * cwr * cc.w;

        float mr4  = DPP(m, 0x124);   // row_ror:4  -> M[(i4-1)&3][j4]
        float mr8  = DPP(m, 0x128);   // row_ror:8  -> M[(i4-2)&3][j4]
        float mr12 = DPP(m, 0x12C);   // row_ror:12 -> M[(i4-3)&3][j4]
        float Uo = fmaf(Br3, mr12, fmaf(Br2, mr8, fmaf(Br1, mr4, Br0 * m)));

        float U0 = DPP(Uo, 0x00);
        float U1 = DPP(Uo, 0x55);
        float U2 = DPP(Uo, 0xAA);
        float U3 = DPP(Uo, 0xFF);

        float4 A0 = *(const float4*)(Ab + b0);
        float4 A1 = *(const float4*)(Ab + 16 + b0);
        float4 A2 = *(const float4*)(Ab + 32 + b0);
        float4 A3 = *(const float4*)(Ab + 48 + b0);
        float ex = fmaf(U3, A3.x, fmaf(U2, A2.x, fmaf(U1, A1.x, U0 * A0.x)));
        float ey = fmaf(U3, A3.y, fmaf(U2, A2.y, fmaf(U1, A1.y, U0 * A0.y)));
        float ez = fmaf(U3, A3.z, fmaf(U2, A2.z, fmaf(U1, A1.z, U0 * A0.z)));
        float ew = fmaf(U3, A3.w, fmaf(U2, A2.w, fmaf(U1, A1.w, U0 * A0.w)));

        float glf  = (lrv + lcv) * lfmask;
        float part = fmaf(glf, glf, fmaf(ew, ew, fmaf(ez, ez, fmaf(ey, ey, ex * ex))));
        float tot  = wave_sum64(part);
        float invr = __builtin_amdgcn_rcpf(__builtin_amdgcn_sqrtf(tot) + 1.f);

        ax = fmaf(ex, invr, ax); ay = fmaf(ey, invr, ay);
        az = fmaf(ez, invr, az); aw = fmaf(ew, invr, aw);
        sgeo = fmaf(glf, invr, sgeo);
        invs += invr;
        sp = fmaf(lcv, pmask, sp);
    };

    for (int base = st; base < en; base += 64) {
        int bcnt = en - base; bcnt = bcnt > 64 ? 64 : bcnt;
        int idx = base + (l < bcnt ? l : bcnt - 1);
        int cvec = ecol[idx];

        int c0 = __builtin_amdgcn_readlane(cvec, 0);
        int k1i = (1 < bcnt) ? 1 : 0;
        int c1 = __builtin_amdgcn_readlane(cvec, k1i);
        float4 cc0 = CCW4[c0 * 4 + j4];
        float  ac0 = attr[(size_t)c0 * 64 + l];
        float  lc0 = lfp[c0 * 16 + l15];
        float4 cc1 = CCW4[c1 * 4 + j4];
        float  ac1 = attr[(size_t)c1 * 64 + l];
        float  lc1 = lfp[c1 * 16 + l15];

        int k = 0;
        for (; k + 1 < bcnt; k += 2) {
            Acbuf[w][0][l] = ac0;
            Acbuf[w][1][l] = ac1;

            // prefetch edges k+2, k+3 (2 iterations of latency cover)
            int k2 = (k + 2 < bcnt) ? k + 2 : bcnt - 1;
            int k3 = (k + 3 < bcnt) ? k + 3 : bcnt - 1;
            int c2 = __builtin_amdgcn_readlane(cvec, k2);
            int c3 = __builtin_amdgcn_readlane(cvec, k3);
            float4 cc2 = CCW4[c2 * 4 + j4];
            float  ac2 = attr[(size_t)c2 * 64 + l];
            float  lc2 = lfp[c2 * 16 + l15];
            float4 cc3 = CCW4[c3 * 4 + j4];
            float  ac3 = attr[(size_t)c3 * 64 + l];
            float  lc3 = lfp[c3 * 16 + l15];

            edge_do(cc0, &Acbuf[w][0][0], lc0);
            edge_do(cc1, &Acbuf[w][1][0], lc1);

            cc0 = cc2; ac0 = ac2; lc0 = lc2;
            cc1 = cc3; ac1 = ac3; lc1 = lc3;
        }
        if (k < bcnt) {   // odd tail
            Acbuf[w][0][l] = ac0;
            edge_do(cc0, &Acbuf[w][0][0], lc0);
        }
    }

    // per-node sums: [0..255] radial (k = a*16+b = l*4+m), [256..264] geo,
    // [265..271] zero, [272] invs, [273..275] pooled sums
    *(float4*)&S[w][l * 4] = make_float4(ax, ay, az, aw);
    if (l < 9)       S[w][256 + l] = sgeo;
    else if (l < 16) S[w][256 + l] = 0.f;
    if (l == 16)     S[w][272] = invs;
    if (l >= 12 && l < 15) S[w][273 + (l - 12)] = sp;
    // S is wave-private: program-order DS deps suffice, no barrier

    float invsum = S[w][272];
    float acc = bvec[l] * invsum;
    const float4* WK4 = (const float4*)wk;
    #pragma unroll 4
    for (int kb = 0; kb < NKB; ++kb) {
        float4 wv = WK4[kb * 64 + l];
        float4 sv = *(const float4*)&S[w][kb * 4];
        acc += wv.x * sv.x + wv.y * sv.y + wv.z * sv.z + wv.w * sv.w;
    }
    out[(size_t)n * OUTC + l] = acc;

    float cntv = (float)deg;
    float invc = __builtin_amdgcn_rcpf(fmaxf(cntv, 1.f));
    if (l < 12) {
        int x = l % 3;
        out[(size_t)n * OUTC + 64 + l] = (cntv * coord[(size_t)n * 12 + l] - S[w][273 + x]) * invc;
    }
}

extern "C" void kernel_launch(void* const* d_in, const int* in_sizes, int n_in,
                              void* d_out, int out_size, void* d_ws, size_t ws_size,
                              hipStream_t stream) {
    const float* coord = (const float*)d_in[0];
    const float* attr  = (const float*)d_in[1];
    const float* cw    = (const float*)d_in[2];
    const float* W     = (const float*)d_in[3];
    const float* bvec  = (const float*)d_in[4];
    const int*   row   = (const int*)d_in[5];
    const int*   col   = (const int*)d_in[6];
    float* out = (float*)d_out;
    float* ws  = (float*)d_ws;
    int E = in_sizes[5];

    float* ccwp = ws + CCW_OFF;
    float* lfp  = ws + LFP_OFF;
    float* wk   = ws + WK_OFF;
    int* counts = (int*)(ws + CNT_OFF);
    int* cursor = (int*)(ws + CUR_OFF);
    int* offs   = (int*)(ws + OFFS_OFF);
    int* tail   = (int*)(ws + TAIL_OFF);

    // deterministic across calls (ws_size fixed) -> graph-safe
    const int bucket = (ws_size >= BUCKET_FLOATS * sizeof(float)) ? 1 : 0;

    hipMemsetAsync(counts, 0, (NN + 4) * sizeof(int), stream);   // counts + cursor

    if (bucket) {
        int* ecolb = tail;                       // NN*CAP
        prep_kernel<<<(E + 255) / 256, 256, 0, stream>>>(
            coord, cw, W, row, col, ccwp, lfp, wk, counts,
            /*perm*/nullptr, ecolb, offs, E, 1);
        edge_kernel<<<NN / 4, 256, 0, stream>>>(coord, attr, bvec, ccwp, lfp, wk,
                                                offs, counts, ecolb, out);
    } else {
        int* perm = tail;                        // EDG
        int* ecol = tail + EDG;                  // EDG
        prep_kernel<<<(E + 255) / 256, 256, 0, stream>>>(
            coord, cw, W, row, col, ccwp, lfp, wk, counts,
            perm, /*ecolb*/nullptr, offs, E, 0);
        scanalloc_kernel<<<NB, 256, 0, stream>>>(counts, cursor, offs);
        scatter_kernel<<<(E + 255) / 256, 256, 0, stream>>>(row, col, offs, perm, ecol, E);
        edge_kernel<<<NN / 4, 256, 0, stream>>>(coord, attr, bvec, ccwp, lfp, wk,
                                                offs, counts, ecol, out);
    }
}